// Round 1
// baseline (95.355 us; speedup 1.0000x reference)
//
#include <hip/hip_runtime.h>

#define B_SZ 8192
#define D_SZ 4096

// ws layout (float index):
//  [0,D)      mean  sum (all)
//  [D,2D)     mean  sum (class 1)
//  [2D,3D)    lsd   sum (all)
//  [3D,4D)    lsd   sum (class 1)
//  [4D,5D)    z     sum (all)
//  [5D,6D)    z     sum (class 1)
//  [6D,7D)    z^2   sum (all)
//  [7D,8D)    z^2   sum (class 1)
//  [8D]=cnt1  [8D+1]=logdet sum all  [8D+2]=logdet sum class1
//  doubles at float index 8D+8 (byte offset 131104, 8-aligned): S0,S1,Lsum0,Lsum1
constexpr int OFF_SCALAR = 8 * D_SZ;
constexpr int OFF_DBL    = 8 * D_SZ + 8;
constexpr size_t WS_CLEAR_BYTES = (size_t)(8 * D_SZ + 8) * 4 + 4 * 8;

__global__ __launch_bounds__(256)
void count_logdet_kernel(const int* __restrict__ target,
                         const float* __restrict__ logdet,
                         float* __restrict__ ws) {
    float c = 0.f, a = 0.f, o = 0.f;
    for (int i = blockIdx.x * 256 + threadIdx.x; i < B_SZ; i += gridDim.x * 256) {
        const float m  = (target[i] == 1) ? 1.f : 0.f;
        const float ld = logdet[i];
        c += m; a += ld; o += ld * m;
    }
    for (int off = 32; off > 0; off >>= 1) {
        c += __shfl_down(c, off);
        a += __shfl_down(a, off);
        o += __shfl_down(o, off);
    }
    if ((threadIdx.x & 63) == 0) {
        atomicAdd(ws + OFF_SCALAR + 0, c);   // exact: integer-valued, < 2^24
        atomicAdd(ws + OFF_SCALAR + 1, a);
        atomicAdd(ws + OFF_SCALAR + 2, o);
    }
}

// Masked column sums of {mean, log_sd, z, z^2}, "all" + "class1" variants.
// grid = (D/512, ROWCHUNKS), block = 256, 2 cols/thread (float2 loads).
__global__ __launch_bounds__(256)
void colsum_kernel(const float* __restrict__ z,
                   const float* __restrict__ mean,
                   const float* __restrict__ lsd,
                   const int* __restrict__ target,
                   float* __restrict__ ws) {
    const int col = blockIdx.x * 512 + threadIdx.x * 2;
    const int rows_per = B_SZ / gridDim.y;
    const int r0 = blockIdx.y * rows_per;

    float am0 = 0, am1 = 0, sm0 = 0, sm1 = 0;  // mean: all, class1
    float al0 = 0, al1 = 0, sl0 = 0, sl1 = 0;  // lsd
    float az0 = 0, az1 = 0, sz0 = 0, sz1 = 0;  // z
    float aq0 = 0, aq1 = 0, sq0 = 0, sq1 = 0;  // z^2

#pragma unroll 4
    for (int i = r0; i < r0 + rows_per; ++i) {
        const size_t base = (size_t)i * D_SZ + col;
        const float2 vm = *(const float2*)(mean + base);
        const float2 vl = *(const float2*)(lsd + base);
        const float2 vz = *(const float2*)(z + base);
        const float  mk = (target[i] == 1) ? 1.f : 0.f;

        am0 += vm.x;                    am1 += vm.y;
        sm0  = fmaf(vm.x, mk, sm0);     sm1  = fmaf(vm.y, mk, sm1);
        al0 += vl.x;                    al1 += vl.y;
        sl0  = fmaf(vl.x, mk, sl0);     sl1  = fmaf(vl.y, mk, sl1);
        az0 += vz.x;                    az1 += vz.y;
        sz0  = fmaf(vz.x, mk, sz0);     sz1  = fmaf(vz.y, mk, sz1);
        const float q0 = vz.x * vz.x,   q1 = vz.y * vz.y;
        aq0 += q0;                      aq1 += q1;
        sq0  = fmaf(q0, mk, sq0);       sq1  = fmaf(q1, mk, sq1);
    }

    atomicAdd(ws + 0 * D_SZ + col, am0); atomicAdd(ws + 0 * D_SZ + col + 1, am1);
    atomicAdd(ws + 1 * D_SZ + col, sm0); atomicAdd(ws + 1 * D_SZ + col + 1, sm1);
    atomicAdd(ws + 2 * D_SZ + col, al0); atomicAdd(ws + 2 * D_SZ + col + 1, al1);
    atomicAdd(ws + 3 * D_SZ + col, sl0); atomicAdd(ws + 3 * D_SZ + col + 1, sl1);
    atomicAdd(ws + 4 * D_SZ + col, az0); atomicAdd(ws + 4 * D_SZ + col + 1, az1);
    atomicAdd(ws + 5 * D_SZ + col, sz0); atomicAdd(ws + 5 * D_SZ + col + 1, sz1);
    atomicAdd(ws + 6 * D_SZ + col, aq0); atomicAdd(ws + 6 * D_SZ + col + 1, aq1);
    atomicAdd(ws + 7 * D_SZ + col, sq0); atomicAdd(ws + 7 * D_SZ + col + 1, sq1);
}

// One thread per column d: write mu/lsd outputs, accumulate scalar sums.
__global__ __launch_bounds__(256)
void finalize_cols_kernel(float* __restrict__ ws, float* __restrict__ out) {
    const int d = blockIdx.x * 256 + threadIdx.x;
    const float cnt1 = ws[OFF_SCALAR];
    const float cnt0 = (float)B_SZ - cnt1;

    const float ma = ws[0 * D_SZ + d], m1 = ws[1 * D_SZ + d];
    const float la = ws[2 * D_SZ + d], l1 = ws[3 * D_SZ + d];
    const float za = ws[4 * D_SZ + d], z1 = ws[5 * D_SZ + d];
    const float qa = ws[6 * D_SZ + d], q1 = ws[7 * D_SZ + d];

    const float mu1 = m1 / cnt1, mu0 = (ma - m1) / cnt0;
    const float ls1 = l1 / cnt1, ls0 = (la - l1) / cnt0;

    // outputs: [0]=prior, [1,1+2D)=mus (class-major), [1+2D,1+4D)=lsds, [1+4D..]=lp
    out[1 + d]             = mu0;
    out[1 + D_SZ + d]      = mu1;
    out[1 + 2 * D_SZ + d]  = ls0;
    out[1 + 3 * D_SZ + d]  = ls1;

    const float z0 = za - z1, q0 = qa - q1;
    const double w0 = 0.5 * exp(-2.0 * (double)ls0);
    const double w1 = 0.5 * exp(-2.0 * (double)ls1);
    // sum_{i in c} (z - mu)^2 = Q_c - 2 mu_c Z_c + cnt_c mu_c^2
    double S0 = w0 * ((double)q0 - 2.0 * (double)mu0 * (double)z0 + (double)cnt0 * (double)mu0 * (double)mu0);
    double S1 = w1 * ((double)q1 - 2.0 * (double)mu1 * (double)z1 + (double)cnt1 * (double)mu1 * (double)mu1);
    double L0 = (double)ls0;
    double L1 = (double)ls1;

    for (int off = 32; off > 0; off >>= 1) {
        S0 += __shfl_down(S0, off);
        S1 += __shfl_down(S1, off);
        L0 += __shfl_down(L0, off);
        L1 += __shfl_down(L1, off);
    }
    if ((threadIdx.x & 63) == 0) {
        double* wd = (double*)(ws + OFF_DBL);
        atomicAdd(wd + 0, S0);
        atomicAdd(wd + 1, S1);
        atomicAdd(wd + 2, L0);
        atomicAdd(wd + 3, L1);
    }
}

__global__ void finalize_scalars_kernel(const float* __restrict__ ws, float* __restrict__ out) {
    const double LOG2PI = 1.8378770664093453;
    const double* wd = (const double*)(ws + OFF_DBL);
    const double S0 = wd[0], S1 = wd[1], L0 = wd[2], L1 = wd[3];
    const double cnt1 = (double)ws[OFF_SCALAR];
    const double cnt0 = (double)B_SZ - cnt1;
    const double ld_all = (double)ws[OFF_SCALAR + 1];
    const double ld1s   = (double)ws[OFF_SCALAR + 2];

    const double ldm1 = ld1s / cnt1;
    const double ldm0 = (ld_all - ld1s) / cnt0;

    const double c0 = -0.5 * LOG2PI * (double)D_SZ - L0;
    const double c1 = -0.5 * LOG2PI * (double)D_SZ - L1;
    const double lp0 = c0 - S0 / cnt0;
    const double lp1 = c1 - S1 / cnt1;

    out[1 + 4 * D_SZ + 0] = (float)lp0;
    out[1 + 4 * D_SZ + 1] = (float)lp1;
    out[0] = (float)(0.5 * ((lp0 + ldm0) + (lp1 + ldm1)));
}

extern "C" void kernel_launch(void* const* d_in, const int* in_sizes, int n_in,
                              void* d_out, int out_size, void* d_ws, size_t ws_size,
                              hipStream_t stream) {
    const float* z      = (const float*)d_in[0];
    const float* mean   = (const float*)d_in[1];
    const float* log_sd = (const float*)d_in[2];
    const int*   target = (const int*)d_in[3];
    const float* logdet = (const float*)d_in[4];
    float* out = (float*)d_out;
    float* ws  = (float*)d_ws;

    hipMemsetAsync(d_ws, 0, WS_CLEAR_BYTES, stream);

    count_logdet_kernel<<<16, 256, 0, stream>>>(target, logdet, ws);

    dim3 grid(D_SZ / 512, 64);   // 8 col-blocks x 64 row-chunks = 512 blocks
    colsum_kernel<<<grid, 256, 0, stream>>>(z, mean, log_sd, target, ws);

    finalize_cols_kernel<<<D_SZ / 256, 256, 0, stream>>>(ws, out);
    finalize_scalars_kernel<<<1, 1, 0, stream>>>(ws, out);
}